// Round 2
// baseline (55759.412 us; speedup 1.0000x reference)
//
#include <hip/hip_runtime.h>
#include <math.h>

#define HD 512
#define TT 512
#define NB 128
#define HSZ (HD * NB)
#define MAGIC 0x13579BDFu

typedef unsigned int uint;

__device__ __forceinline__ float sigm(float v) { return 1.0f / (1.0f + __expf(-v)); }

// Two-level monotonic barrier over the 128 unit-group WGs of one batch-group.
// mybar lines (128B apart): 0..3 sub-counters (32 WGs each), 4 root, 5 gen, 6 ready.
__device__ __forceinline__ void gbar(uint* mybar, int subid, uint n) {
    __threadfence();              // release: publish my h writes (agent scope)
    __syncthreads();
    if (threadIdx.x == 0) {
        uint old = __hip_atomic_fetch_add(mybar + subid * 32, 1u,
                                          __ATOMIC_ACQ_REL, __HIP_MEMORY_SCOPE_AGENT);
        if (old == 32u * (n + 1u) - 1u) {
            uint r = __hip_atomic_fetch_add(mybar + 4 * 32, 1u,
                                            __ATOMIC_ACQ_REL, __HIP_MEMORY_SCOPE_AGENT);
            if (r == 4u * (n + 1u) - 1u)
                __hip_atomic_store(mybar + 5 * 32, n + 1u,
                                   __ATOMIC_RELEASE, __HIP_MEMORY_SCOPE_AGENT);
        }
        while (__hip_atomic_load(mybar + 5 * 32, __ATOMIC_RELAXED,
                                 __HIP_MEMORY_SCOPE_AGENT) < n + 1u)
            __builtin_amdgcn_s_sleep(2);
    }
    __syncthreads();
    __threadfence();              // acquire: invalidate stale h in L1/L2
}

// 256 WGs = 2 batch-groups x 128 unit-groups. 256 threads = 4 waves.
// Wave w of WG handles hidden unit uglob = wgu*4 + w for 64 batch columns.
__global__ __launch_bounds__(256, 1) void gru_ae(
    const float* __restrict__ x,
    const float* __restrict__ eWi, const float* __restrict__ eWh,
    const float* __restrict__ ebi, const float* __restrict__ ebh,
    const float* __restrict__ dWi, const float* __restrict__ dWh,
    const float* __restrict__ dbi, const float* __restrict__ dbh,
    const float* __restrict__ linW, const float* __restrict__ linb,
    float* __restrict__ hbuf,   // 2 * 512*128 floats
    uint* __restrict__ bar,     // 2 * 8 lines * 32 uints
    float* __restrict__ out)
{
    const int wg     = blockIdx.x;
    const int bg     = wg >> 7;                                   // 0..1
    const int wgu    = wg & 127;                                  // 0..127
    const int lane   = threadIdx.x & 63;
    const int ulocal = __builtin_amdgcn_readfirstlane(threadIdx.x >> 6); // 0..3
    const int uglob  = wgu * 4 + ulocal;                          // 0..511
    const int col    = bg * 64 + lane;                            // batch 0..127
    const int subid  = wgu >> 5;
    uint* mybar = bar + bg * 8 * 32;

    // ---- init barrier counters (one WG per batch-group); d_ws is poisoned ----
    if (wgu == 0 && threadIdx.x == 0) {
        for (int i = 0; i < 6; ++i)
            __hip_atomic_store(mybar + i * 32, 0u, __ATOMIC_RELAXED, __HIP_MEMORY_SCOPE_AGENT);
        __hip_atomic_store(mybar + 6 * 32, MAGIC, __ATOMIC_RELEASE, __HIP_MEMORY_SCOPE_AGENT);
    }
    if (threadIdx.x == 0) {
        while (__hip_atomic_load(mybar + 6 * 32, __ATOMIC_ACQUIRE,
                                 __HIP_MEMORY_SCOPE_AGENT) != MAGIC)
            __builtin_amdgcn_s_sleep(2);
    }
    __syncthreads();

    // zero h0 in buf0: this WG's 4 rows x 64 cols
    hbuf[uglob * NB + col] = 0.0f;

    uint bn = 0;
    gbar(mybar, subid, bn); ++bn;

    // ---- wave-uniform (scalar-path) weight rows & gate constants: encoder ----
    const float* ewr = eWh + (0 * HD + uglob) * HD;
    const float* ewz = eWh + (1 * HD + uglob) * HD;
    const float* ewn = eWh + (2 * HD + uglob) * HD;
    {
        const float wi_r = eWi[uglob], wi_z = eWi[HD + uglob], wi_n = eWi[2 * HD + uglob];
        const float cr = ebi[uglob] + ebh[uglob];
        const float cz = ebi[HD + uglob] + ebh[HD + uglob];
        const float bin = ebi[2 * HD + uglob], bhn = ebh[2 * HD + uglob];

        int p = 0;
        for (int s = 0; s < TT; ++s) {
            const float* ho = hbuf + p * HSZ;
            float*       hw = hbuf + (p ^ 1) * HSZ;
            float ar = 0.f, az = 0.f, an = 0.f;
            #pragma unroll 8
            for (int k = 0; k < HD; ++k) {
                float h = ho[k * NB + col];
                ar = fmaf(ewr[k], h, ar);
                az = fmaf(ewz[k], h, az);
                an = fmaf(ewn[k], h, an);
            }
            float xt    = x[col * TT + s];
            float hprev = ho[uglob * NB + col];
            float r = sigm(fmaf(xt, wi_r, cr) + ar);
            float z = sigm(fmaf(xt, wi_z, cz) + az);
            float n = tanhf(fmaf(xt, wi_n, bin) + r * (an + bhn));
            float hv = fmaf(z, hprev - n, n);
            hw[uglob * NB + col] = hv;
            p ^= 1;
            gbar(mybar, subid, bn); ++bn;
        }

        // ---- decoder ----
        const float* dwr = dWh + (0 * HD + uglob) * HD;
        const float* dwz = dWh + (1 * HD + uglob) * HD;
        const float* dwn = dWh + (2 * HD + uglob) * HD;
        const float wi_r2 = dWi[uglob], wi_z2 = dWi[HD + uglob], wi_n2 = dWi[2 * HD + uglob];
        const float cr2 = dbi[uglob] + dbh[uglob];
        const float cz2 = dbi[HD + uglob] + dbh[HD + uglob];
        const float bin2 = dbi[2 * HD + uglob], bhn2 = dbh[2 * HD + uglob];
        const float lb = linb[0];

        for (int s = 0; s < TT; ++s) {
            const float* ho = hbuf + p * HSZ;
            float*       hw = hbuf + (p ^ 1) * HSZ;
            float ar = 0.f, az = 0.f, an = 0.f, yd = 0.f;
            #pragma unroll 8
            for (int k = 0; k < HD; ++k) {
                float h = ho[k * NB + col];
                ar = fmaf(dwr[k], h, ar);
                az = fmaf(dwz[k], h, az);
                an = fmaf(dwn[k], h, an);
                yd = fmaf(linW[k], h, yd);
            }
            float y = yd + lb;                     // y_{s-1}: this step's input
            if (s > 0 && uglob == 0)
                out[col * TT + (TT - s)] = y;      // emit y_{s-1} at 511-(s-1)
            float hprev = ho[uglob * NB + col];
            float r = sigm(fmaf(y, wi_r2, cr2) + ar);
            float z = sigm(fmaf(y, wi_z2, cz2) + az);
            float n = tanhf(fmaf(y, wi_n2, bin2) + r * (an + bhn2));
            float hv = fmaf(z, hprev - n, n);
            hw[uglob * NB + col] = hv;
            p ^= 1;
            gbar(mybar, subid, bn); ++bn;
        }

        // final y_511 -> out[:, 0]
        if (uglob == 0) {
            const float* ho = hbuf + p * HSZ;
            float yd = 0.f;
            #pragma unroll 8
            for (int k = 0; k < HD; ++k)
                yd = fmaf(linW[k], ho[k * NB + col], yd);
            out[col * TT + 0] = yd + lb;
        }
    }
}

extern "C" void kernel_launch(void* const* d_in, const int* in_sizes, int n_in,
                              void* d_out, int out_size, void* d_ws, size_t ws_size,
                              hipStream_t stream) {
    const float* x    = (const float*)d_in[0];
    const float* eWi  = (const float*)d_in[1];
    const float* eWh  = (const float*)d_in[2];
    const float* ebi  = (const float*)d_in[3];
    const float* ebh  = (const float*)d_in[4];
    const float* dWi  = (const float*)d_in[5];
    const float* dWh  = (const float*)d_in[6];
    const float* dbi  = (const float*)d_in[7];
    const float* dbh  = (const float*)d_in[8];
    const float* linW = (const float*)d_in[9];
    const float* linb = (const float*)d_in[10];
    float* out = (float*)d_out;

    float* hbuf = (float*)d_ws;                    // 2*512*128 floats = 512 KB
    uint*  bar  = (uint*)((char*)d_ws + 2 * HSZ * sizeof(float));  // 2 KB

    gru_ae<<<dim3(256), dim3(256), 0, stream>>>(x, eWi, eWh, ebi, ebh,
                                                dWi, dWh, dbi, dbh,
                                                linW, linb, hbuf, bar, out);
}